// Round 6
// baseline (1084.850 us; speedup 1.0000x reference)
//
#include <hip/hip_runtime.h>
#include <hip/hip_bf16.h>

typedef __bf16 bf16_t;
typedef __bf16 bf16x4 __attribute__((ext_vector_type(4)));
typedef __bf16 bf16x8 __attribute__((ext_vector_type(8)));
typedef float f32x4 __attribute__((ext_vector_type(4)));

union FragU { bf16x8 v; bf16x4 h[2]; };
union F4U { float4 v; float f[4]; };

constexpr int BB = 32, SS = 512, DD = 512, FFD = 2048, LL = 4, HH = 8;

// Fragment-order permutation of k within each 32-elem chunk: granule order
// [0,4,1,5,2,6,3,7] -> MFMA fragment g (k = 4g..4g+3, 16+4g..16+4g+3) is one
// contiguous 16B block at byte offset g*16 of the 64B chunk.
__device__ __forceinline__ int permk(int k) {
  int g = (k >> 2) & 7;
  int pos = (g < 4) ? (g << 1) : (((g - 4) << 1) | 1);
  return (k & ~31) | (pos << 2) | (k & 3);
}

__device__ __forceinline__ void gload_lds16(const bf16_t* g, bf16_t* l) {
  __builtin_amdgcn_global_load_lds(
      (const __attribute__((address_space(1))) void*)g,
      (__attribute__((address_space(3))) void*)l, 16, 0, 0);
}

template<int N> __device__ __forceinline__ void vmwait() {
  asm volatile("s_waitcnt vmcnt(%0)" :: "n"(N) : "memory");
}

#define MFMA_ACC(d, a, b) d = __builtin_amdgcn_mfma_f32_16x16x32_bf16((a).v, (b).v, d, 0, 0, 0)

// ---------------- positional-embedding table [S][D] ----------------
__global__ void pe_kernel(float* __restrict__ pe) {
  int idx = blockIdx.x * blockDim.x + threadIdx.x;  // pair index
  if (idx >= SS * DD / 2) return;
  int p = idx % (DD / 2);
  int s = idx / (DD / 2);
  float div = expf((float)(2 * p) * (-9.210340371976184f / (float)DD));
  float a = (float)s * div;
  pe[s * DD + 2 * p]     = sinf(a);
  pe[s * DD + 2 * p + 1] = cosf(a);
}

// ---------------- transpose-cast: src [K][N] f32 -> dst [N][K]_perm bf16 ----
__global__ __launch_bounds__(256) void tcast_kernel(const float* __restrict__ src,
                                                    bf16_t* __restrict__ dst,
                                                    int K, int N) {
  __shared__ float tile[32][33];
  size_t mat = (size_t)blockIdx.z * (size_t)K * (size_t)N;
  int k0 = blockIdx.y * 32, n0 = blockIdx.x * 32;
  int t = threadIdx.x;
  int r = t >> 3, c4 = (t & 7) * 4;
  const float4 v = *reinterpret_cast<const float4*>(&src[mat + (size_t)(k0 + r) * N + n0 + c4]);
  tile[r][c4 + 0] = v.x; tile[r][c4 + 1] = v.y; tile[r][c4 + 2] = v.z; tile[r][c4 + 3] = v.w;
  __syncthreads();
  bf16x4 o;
  o[0] = (bf16_t)tile[c4 + 0][r];
  o[1] = (bf16_t)tile[c4 + 1][r];
  o[2] = (bf16_t)tile[c4 + 2][r];
  o[3] = (bf16_t)tile[c4 + 3][r];
  *reinterpret_cast<bf16x4*>(&dst[mat + permk((n0 + r) * K + k0 + c4)]) = o;
}

// ---------------- x = q + pe (f32 + bf16_perm), yb = bf16_perm(qa + pe) ----
__global__ void addpe_kernel(const float* __restrict__ q, const float* __restrict__ qa,
                             const float* __restrict__ pe,
                             float* __restrict__ x, bf16_t* __restrict__ xb,
                             bf16_t* __restrict__ yb) {
  int i = blockIdx.x * blockDim.x + threadIdx.x;  // float4 index
  int pei = i & (SS * DD / 4 - 1);
  float4 pv = reinterpret_cast<const float4*>(pe)[pei];
  float4 qv = reinterpret_cast<const float4*>(q)[i];
  float4 av = reinterpret_cast<const float4*>(qa)[i];
  float4 xv = make_float4(qv.x + pv.x, qv.y + pv.y, qv.z + pv.z, qv.w + pv.w);
  float4 yv = make_float4(av.x + pv.x, av.y + pv.y, av.z + pv.z, av.w + pv.w);
  reinterpret_cast<float4*>(x)[i] = xv;
  bf16x4 xo, yo;
  xo[0] = (bf16_t)xv.x; xo[1] = (bf16_t)xv.y; xo[2] = (bf16_t)xv.z; xo[3] = (bf16_t)xv.w;
  yo[0] = (bf16_t)yv.x; yo[1] = (bf16_t)yv.y; yo[2] = (bf16_t)yv.z; yo[3] = (bf16_t)yv.w;
  int kp = permk(4 * i);
  *reinterpret_cast<bf16x4*>(&xb[kp]) = xo;
  *reinterpret_cast<bf16x4*>(&yb[kp]) = yo;
}

// ---------------- 8-phase GEMM: C[M,N] = A[M,K]_perm @ Bt[N,K]_perm^T + bias ----
// BM=256, BK=64, 512 threads (8 waves 2x4). Double-buffered LDS; stage(T+2) issued
// in tile T's last phase (after all reads of that buffer); per-tile wait = vmcnt(LOADS)
// (never 0 in steady state). Phases = C-quadrants with setprio'd MFMA clusters.
// XOR-block swizzle on LDS rows (source-side pre-swizzle, matching read XOR).
template<int BN, bool OUT_BF16, bool RELU>
__global__ __launch_bounds__(512, 2) void gemm8_kernel(const bf16_t* __restrict__ A,
                                                       const bf16_t* __restrict__ Bt,
                                                       const float* __restrict__ bias,
                                                       void* __restrict__ Cout,
                                                       int N, int K, int nnt) {
  constexpr int BM = 256, BK = 64;
  constexpr int WN = BN / 4;           // per-wave N extent
  constexpr int NF = WN / 16;          // n-frags per wave (4 or 2)
  constexpr int AL = 4, BL = BN / 64;  // stage rounds (16B/thread each)
  constexpr int LOADS = AL + BL;       // outstanding loads per staged tile
  __shared__ bf16_t a_s[2][BM * BK];
  __shared__ bf16_t b_s[2][BN * BK];
  const int t = threadIdx.x;
  const int bid = blockIdx.x, nwg = gridDim.x;
  const int wg = (bid & 7) * (nwg >> 3) + (bid >> 3);   // bijective XCD swizzle
  const int m0 = (wg / nnt) * BM, n0 = (wg % nnt) * BN;
  const int l = t & 63, w = t >> 6, g = l >> 4, ln = l & 15, lnx = l & 7;
  const int wr = w >> 2, wc = w & 3;   // 2x4 wave grid
  // staging: round i covers rows i*64+(t>>3), 16B pos t&7; source block pre-swizzled
  const int tr8 = t >> 3;
  const int bsrc = ((t & 7) ^ (tr8 & 7)) * 8;
  const bf16_t* Asrc = A + (size_t)(m0 + tr8) * K + bsrc;
  const bf16_t* Bsrc = Bt + (size_t)(n0 + tr8) * K + bsrc;
  const size_t rstr = (size_t)64 * K;

  auto STAGE = [&](int p, int kt) {
    const int k0 = kt << 6;
#pragma unroll
    for (int i = 0; i < AL; i++) gload_lds16(Asrc + k0 + i * rstr, &a_s[p][(i * 512 + t) * 8]);
#pragma unroll
    for (int i = 0; i < BL; i++) gload_lds16(Bsrc + k0 + i * rstr, &b_s[p][(i * 512 + t) * 8]);
  };
  auto rdA = [&](int p, int mh, int mi, int kc) -> bf16x8 {
    return *reinterpret_cast<const bf16x8*>(
        &a_s[p][(wr * 128 + mh * 64 + mi * 16 + ln) * 64 + ((kc * 4 + g) ^ lnx) * 8]);
  };
  auto rdB = [&](int p, int nf, int kc) -> bf16x8 {
    return *reinterpret_cast<const bf16x8*>(
        &b_s[p][(wc * WN + nf * 16 + ln) * 64 + ((kc * 4 + g) ^ lnx) * 8]);
  };

  f32x4 acc[8][NF] = {};
  const int NT = K >> 6;
  STAGE(0, 0);
  STAGE(1, 1);
  vmwait<LOADS>();
  __syncthreads();

  for (int T = 0; T < NT; T++) {
    const int p = T & 1;
    if constexpr (BN == 256) {
      FragU fa[8], fbA[4], fbB[4];
      // P0: read A(mh=0), B(nh=0); MFMA quad(0,0)
#pragma unroll
      for (int kc = 0; kc < 2; kc++) {
#pragma unroll
        for (int mi = 0; mi < 4; mi++) fa[kc * 4 + mi].v = rdA(p, 0, mi, kc);
#pragma unroll
        for (int ni = 0; ni < 2; ni++) fbA[kc * 2 + ni].v = rdB(p, ni, kc);
      }
      __syncthreads();
      __builtin_amdgcn_s_setprio(1);
#pragma unroll
      for (int kc = 0; kc < 2; kc++)
#pragma unroll
        for (int mi = 0; mi < 4; mi++)
#pragma unroll
          for (int ni = 0; ni < 2; ni++)
            MFMA_ACC(acc[mi][ni], fa[kc * 4 + mi], fbA[kc * 2 + ni]);
      __builtin_amdgcn_s_setprio(0);
      __syncthreads();
      // P1: read B(nh=1); MFMA quad(0,1)
#pragma unroll
      for (int kc = 0; kc < 2; kc++)
#pragma unroll
        for (int ni = 0; ni < 2; ni++) fbB[kc * 2 + ni].v = rdB(p, 2 + ni, kc);
      __syncthreads();
      __builtin_amdgcn_s_setprio(1);
#pragma unroll
      for (int kc = 0; kc < 2; kc++)
#pragma unroll
        for (int mi = 0; mi < 4; mi++)
#pragma unroll
          for (int ni = 0; ni < 2; ni++)
            MFMA_ACC(acc[mi][2 + ni], fa[kc * 4 + mi], fbB[kc * 2 + ni]);
      __builtin_amdgcn_s_setprio(0);
      __syncthreads();
      // P2: read A(mh=1); MFMA quad(1,1)
#pragma unroll
      for (int kc = 0; kc < 2; kc++)
#pragma unroll
        for (int mi = 0; mi < 4; mi++) fa[kc * 4 + mi].v = rdA(p, 1, mi, kc);
      __syncthreads();
      __builtin_amdgcn_s_setprio(1);
#pragma unroll
      for (int kc = 0; kc < 2; kc++)
#pragma unroll
        for (int mi = 0; mi < 4; mi++)
#pragma unroll
          for (int ni = 0; ni < 2; ni++)
            MFMA_ACC(acc[4 + mi][2 + ni], fa[kc * 4 + mi], fbB[kc * 2 + ni]);
      __builtin_amdgcn_s_setprio(0);
      __syncthreads();
      // P3: stage(T+2) into freed buffer; MFMA quad(1,0); counted vmcnt
      if (T + 2 < NT) STAGE(p, T + 2);
      __syncthreads();
      __builtin_amdgcn_s_setprio(1);
#pragma unroll
      for (int kc = 0; kc < 2; kc++)
#pragma unroll
        for (int mi = 0; mi < 4; mi++)
#pragma unroll
          for (int ni = 0; ni < 2; ni++)
            MFMA_ACC(acc[4 + mi][ni], fa[kc * 4 + mi], fbA[kc * 2 + ni]);
      __builtin_amdgcn_s_setprio(0);
      if (T + 1 < NT) { if (T + 2 < NT) vmwait<LOADS>(); else vmwait<0>(); }
      __syncthreads();
    } else {
      FragU fa0[8], fa1[8], fb[4];
      // P0: read A(mh=0) + all B; MFMA (mh0, kc0)
#pragma unroll
      for (int kc = 0; kc < 2; kc++) {
#pragma unroll
        for (int mi = 0; mi < 4; mi++) fa0[kc * 4 + mi].v = rdA(p, 0, mi, kc);
#pragma unroll
        for (int ni = 0; ni < 2; ni++) fb[kc * 2 + ni].v = rdB(p, ni, kc);
      }
      __syncthreads();
      __builtin_amdgcn_s_setprio(1);
#pragma unroll
      for (int mi = 0; mi < 4; mi++)
#pragma unroll
        for (int ni = 0; ni < 2; ni++)
          MFMA_ACC(acc[mi][ni], fa0[mi], fb[ni]);
      __builtin_amdgcn_s_setprio(0);
      __syncthreads();
      // P1: read A(mh=1); MFMA (mh0, kc1)
#pragma unroll
      for (int kc = 0; kc < 2; kc++)
#pragma unroll
        for (int mi = 0; mi < 4; mi++) fa1[kc * 4 + mi].v = rdA(p, 1, mi, kc);
      __syncthreads();
      __builtin_amdgcn_s_setprio(1);
#pragma unroll
      for (int mi = 0; mi < 4; mi++)
#pragma unroll
        for (int ni = 0; ni < 2; ni++)
          MFMA_ACC(acc[mi][ni], fa0[4 + mi], fb[2 + ni]);
      __builtin_amdgcn_s_setprio(0);
      __syncthreads();
      // P2: stage(T+2); MFMA (mh1, both kc); counted vmcnt
      if (T + 2 < NT) STAGE(p, T + 2);
      __syncthreads();
      __builtin_amdgcn_s_setprio(1);
#pragma unroll
      for (int kc = 0; kc < 2; kc++)
#pragma unroll
        for (int mi = 0; mi < 4; mi++)
#pragma unroll
          for (int ni = 0; ni < 2; ni++)
            MFMA_ACC(acc[4 + mi][ni], fa1[kc * 4 + mi], fb[kc * 2 + ni]);
      __builtin_amdgcn_s_setprio(0);
      if (T + 1 < NT) { if (T + 2 < NT) vmwait<LOADS>(); else vmwait<0>(); }
      __syncthreads();
    }
  }

#pragma unroll
  for (int nf = 0; nf < NF; nf++) {
    const int col = n0 + wc * WN + nf * 16 + ln;
    const float bv = bias[col];
    const int colp = OUT_BF16 ? permk(col) : col;
#pragma unroll
    for (int mf = 0; mf < 8; mf++)
#pragma unroll
      for (int r = 0; r < 4; r++) {
        int row = m0 + wr * 128 + mf * 16 + g * 4 + r;
        float o = acc[mf][nf][r] + bv;
        if (RELU) o = fmaxf(o, 0.f);
        if (OUT_BF16)
          reinterpret_cast<bf16_t*>(Cout)[(size_t)row * N + colp] = (bf16_t)o;
        else
          reinterpret_cast<float*>(Cout)[(size_t)row * N + col] = o;
      }
  }
}

// ---------------- residual + LayerNorm: xout=LN(xin+addv), bf16_perm copy ----
__global__ __launch_bounds__(256) void ln_kernel(const float* __restrict__ xin,
                                                 const float* __restrict__ addv,
                                                 const float* __restrict__ gamma,
                                                 const float* __restrict__ beta,
                                                 float* __restrict__ xout,
                                                 bf16_t* __restrict__ xbout) {
  int row = blockIdx.x * 4 + (threadIdx.x >> 6);
  int l = threadIdx.x & 63;
  const float* px = xin + (size_t)row * DD;
  const float* pa = addv + (size_t)row * DD;
  float vals[8];
  float s = 0.f;
#pragma unroll
  for (int i = 0; i < 2; i++) {
    float4 a = reinterpret_cast<const float4*>(px)[l * 2 + i];
    float4 b = reinterpret_cast<const float4*>(pa)[l * 2 + i];
    vals[i * 4 + 0] = a.x + b.x;
    vals[i * 4 + 1] = a.y + b.y;
    vals[i * 4 + 2] = a.z + b.z;
    vals[i * 4 + 3] = a.w + b.w;
  }
#pragma unroll
  for (int j = 0; j < 8; j++) s += vals[j];
#pragma unroll
  for (int off = 1; off < 64; off <<= 1) s += __shfl_xor(s, off, 64);
  float mean = s * (1.f / DD);
  float sq = 0.f;
#pragma unroll
  for (int j = 0; j < 8; j++) { float d = vals[j] - mean; sq += d * d; }
#pragma unroll
  for (int off = 1; off < 64; off <<= 1) sq += __shfl_xor(sq, off, 64);
  float rstd = rsqrtf(sq * (1.f / DD) + 1e-5f);
#pragma unroll
  for (int i = 0; i < 2; i++) {
    F4U o; bf16x4 ob;
#pragma unroll
    for (int j = 0; j < 4; j++) {
      int colj = l * 8 + i * 4 + j;
      float v = (vals[i * 4 + j] - mean) * rstd * gamma[colj] + beta[colj];
      o.f[j] = v;
      ob[j] = (bf16_t)v;
    }
    reinterpret_cast<float4*>(xout + (size_t)row * DD)[l * 2 + i] = o.v;
    *reinterpret_cast<bf16x4*>(&xbout[(size_t)row * DD + permk(l * 8 + i * 4)]) = ob;
  }
}

// ---------------- V transpose: vbuf [B*S][512]_perm -> vtg [B*H*64][S] ----------------
__global__ __launch_bounds__(256) void vtrans_kernel(const bf16_t* __restrict__ vbuf,
                                                     bf16_t* __restrict__ vtg) {
  __shared__ bf16_t t_s[64][72];
  const int jt = blockIdx.x, h = blockIdx.y, b = blockIdx.z;
  const int t = threadIdx.x;
#pragma unroll
  for (int i = 0; i < 2; i++) {
    int c = t + i * 256;
    int s = c >> 3, bb = c & 7;
    FragU vr;
    vr.v = *reinterpret_cast<const bf16x8*>(
        &vbuf[(size_t)(b * SS + jt * 64 + s) * DD + h * 64 + bb * 8]);
    int cc = (bb >> 2) * 32, p = (bb & 3) * 4;   // un-permk: block bb = orig granules (p,p+4)
    *reinterpret_cast<bf16x4*>(&t_s[s][cc + p]) = vr.h[0];
    *reinterpret_cast<bf16x4*>(&t_s[s][cc + 16 + p]) = vr.h[1];
  }
  __syncthreads();
#pragma unroll
  for (int i = 0; i < 2; i++) {
    int c = t + i * 256;
    int d = c >> 3, blkx = c & 7;
    int blk = blkx ^ (d & 7);
    int js = blk >> 2, g = blk & 3;
    FragU o;
#pragma unroll
    for (int e = 0; e < 4; e++) o.v[e] = t_s[js * 32 + g * 4 + e][d];
#pragma unroll
    for (int e = 0; e < 4; e++) o.v[e + 4] = t_s[js * 32 + 16 + g * 4 + e][d];
    *reinterpret_cast<bf16x8*>(
        &vtg[((size_t)((b * HH + h) * 64 + d)) * SS + jt * 64 + blkx * 8]) = o.v;
  }
}

// ---------------- fused causal attention, swapped-QK^T (S^T), V^T pre-staged ----------
__global__ __launch_bounds__(256) void attn_kernel(const bf16_t* __restrict__ qk,
                                                   const bf16_t* __restrict__ vtg,
                                                   bf16_t* __restrict__ outp,
                                                   const float* __restrict__ bfp) {
  __shared__ bf16_t k_s[64 * 64];    // K tile, block-XOR pre-swizzled via source
  __shared__ bf16_t v_t[64 * 64];    // V^T tile, swizzle baked in global layout
  const int bx = blockIdx.x, h = blockIdx.y, b = blockIdx.z;
  const int t = threadIdx.x, l = t & 63, w = t >> 6, g = l >> 4, ln = l & 15;
  const float sc = 0.125f * (1.f + bfp[0]);
  const size_t base = ((size_t)b * SS) * DD + h * 64;
  const bf16_t* vbase = vtg + ((size_t)((b * HH + h) * 64)) * SS;
  const int NQT = SS / 64;

  for (int pass = 0; pass < 2; pass++) {
    const int qt = pass ? (NQT - 1 - bx) : bx;
    const int i0 = qt * 64;
    FragU qB[2];   // wave's 16 q-rows as B-operand: lane(g,ln) = Q[i0+w*16+ln][frag g]
    {
      const bf16_t* qp = qk + base + (size_t)(i0 + w * 16 + ln) * DD;
      qB[0].v = *reinterpret_cast<const bf16x8*>(&qp[g * 8]);
      qB[1].v = *reinterpret_cast<const bf16x8*>(&qp[32 + g * 8]);
    }
    float m = -1e30f, lrow = 0.f;   // softmax state for row i = i0 + w*16 + ln
    f32x4 acc[4] = {};              // O rows i0+w*16+g*4+r, cols d = nd*16+ln
    const int iql = w * 16 + ln;

    for (int kt = 0; kt <= qt; kt++) {
      const int j0 = kt * 64;
      __syncthreads();
      {
        int c1 = t + 256;
        int jr0 = t >> 3, bb0 = t & 7;
        int jr1 = c1 >> 3, bb1 = c1 & 7;
        gload_lds16(qk + base + (size_t)(j0 + jr0) * DD + ((bb0 ^ (jr0 & 7)) * 8), &k_s[t * 8]);
        gload_lds16(qk + base + (size_t)(j0 + jr1) * DD + ((bb1 ^ (jr1 & 7)) * 8), &k_s[c1 * 8]);
        gload_lds16(vbase + (size_t)jr0 * SS + j0 + bb0 * 8, &v_t[t * 8]);
        gload_lds16(vbase + (size_t)jr1 * SS + j0 + bb1 * 8, &v_t[c1 * 8]);
      }
      asm volatile("s_waitcnt vmcnt(0)" ::: "memory");
      __syncthreads();
      // S^T: sfr[nj] holds rows j = j0+nj*16+g*4+r, col i = i0+w*16+ln
      f32x4 sfr[4] = {};
#pragma unroll
      for (int ks = 0; ks < 2; ks++)
#pragma unroll
        for (int nj = 0; nj < 4; nj++) {
          int jc = nj * 16 + ln;
          FragU ka;
          ka.v = *reinterpret_cast<const bf16x8*>(&k_s[jc * 64 + (((ks * 4 + g) ^ (jc & 7)) * 8)]);
          sfr[nj] = __builtin_amdgcn_mfma_f32_16x16x32_bf16(ka.v, qB[ks].v, sfr[nj], 0, 0, 0);
        }
      if (kt == qt) {   // strictly-causal mask, diag tile only
#pragma unroll
        for (int nj = 0; nj < 4; nj++)
#pragma unroll
          for (int r = 0; r < 4; r++)
            if (nj * 16 + g * 4 + r >= iql) sfr[nj][r] = -1e30f;
      }
      float pm = -1e30f;
#pragma unroll
      for (int nj = 0; nj < 4; nj++)
#pragma unroll
        for (int r = 0; r < 4; r++) pm = fmaxf(pm, sfr[nj][r]);
      pm = fmaxf(pm, __shfl_xor(pm, 16, 64));
      pm = fmaxf(pm, __shfl_xor(pm, 32, 64));
      float mnew = fmaxf(m, pm);
      float fac = __expf(sc * (m - mnew));
      m = mnew;
      float ps = 0.f;
#pragma unroll
      for (int nj = 0; nj < 4; nj++)
#pragma unroll
        for (int r = 0; r < 4; r++) {
          float p = __expf(sc * (sfr[nj][r] - m));   // masked -> exp(-inf) = 0
          sfr[nj][r] = p;
          ps += p;
        }
      ps += __shfl_xor(ps, 16, 64);
      ps += __shfl_xor(ps, 32, 64);
      lrow = lrow * fac + ps;
      float facr[4];
#pragma unroll
      for (int r = 0; r < 4; r++) facr[r] = __shfl(fac, g * 4 + r, 64);
#pragma unroll
      for (int nd = 0; nd < 4; nd++)
#pragma unroll
        for (int r = 0; r < 4; r++) acc[nd][r] *= facr[r];
      // P fragments: A-operand layout == swapped-MFMA C layout (same lane)
      FragU pa[2];
#pragma unroll
      for (int js = 0; js < 2; js++)
#pragma unroll
        for (int kk = 0; kk < 4; kk++) {
          pa[js].v[kk]     = (bf16_t)sfr[js * 2][kk];
          pa[js].v[kk + 4] = (bf16_t)sfr[js * 2 + 1][kk];
        }
#pragma unroll
      for (int js = 0; js < 2; js++)
#pragma unroll
        for (int nd = 0; nd < 4; nd++) {
          int d = nd * 16 + ln;
          FragU vb;
          vb.v = *reinterpret_cast<const bf16x8*>(&v_t[d * 64 + (((js * 4 + g) ^ (d & 7)) * 8)]);
          acc[nd] = __builtin_amdgcn_mfma_f32_16x16x32_bf16(pa[js].v, vb.v, acc[nd], 0, 0, 0);
        }
    }
    float lr[4];
#pragma unroll
    for (int r = 0; r < 4; r++) lr[r] = __shfl(lrow, g * 4 + r, 64);
    const int orow0 = i0 + w * 16 + g * 4;
#pragma unroll
    for (int nd = 0; nd < 4; nd++) {
      const int colp = permk(nd * 16 + ln);
#pragma unroll
      for (int r = 0; r < 4; r++) {
        int grow = orow0 + r;
        float o = (grow > 0 && lr[r] > 0.f) ? acc[nd][r] / lr[r] : 0.f;  // row0 zero_pad
        outp[base + (size_t)grow * DD + colp] = (bf16_t)o;
      }
    }
  }
}

extern "C" void kernel_launch(void* const* d_in, const int* in_sizes, int n_in,
                              void* d_out, int out_size, void* d_ws, size_t ws_size,
                              hipStream_t stream) {
  const float* q_emb  = (const float*)d_in[0];
  const float* qa_emb = (const float*)d_in[1];
  const float* bfp    = (const float*)d_in[2];
  const float* Wk  = (const float*)d_in[3];
  const float* bk  = (const float*)d_in[4];
  const float* Wv  = (const float*)d_in[5];
  const float* bv  = (const float*)d_in[6];
  const float* Wo  = (const float*)d_in[7];
  const float* bo  = (const float*)d_in[8];
  const float* g1  = (const float*)d_in[9];
  const float* be1 = (const float*)d_in[10];
  const float* W1  = (const float*)d_in[11];
  const float* b1  = (const float*)d_in[12];
  const float* W2  = (const float*)d_in[13];
  const float* b2  = (const float*)d_in[14];
  const float* g2  = (const float*)d_in[15];
  const float* be2 = (const float*)d_in[16];
  float* out = (float*)d_out;
  (void)in_sizes; (void)n_in; (void)out_size; (void)ws_size;

  char* wsp = (char*)d_ws;
  size_t off = 0;
  auto alloc = [&](size_t bytes) -> void* {
    void* p = wsp + off;
    off += (bytes + 255) & ~(size_t)255;
    return p;
  };
  const size_t BSD = (size_t)BB * SS * DD;
  float*  pe   = (float*) alloc((size_t)SS * DD * 4);
  float*  x    = (float*) alloc(BSD * 4);
  float*  tmp  = (float*) alloc(BSD * 4);
  bf16_t* xb   = (bf16_t*)alloc(BSD * 2);
  bf16_t* yb   = (bf16_t*)alloc(BSD * 2);
  bf16_t* qkb  = (bf16_t*)alloc(BSD * 2);
  bf16_t* vbuf = (bf16_t*)alloc(BSD * 2);
  bf16_t* vtg  = (bf16_t*)alloc(BSD * 2);
  bf16_t* atb  = (bf16_t*)alloc(BSD * 2);
  bf16_t* h1   = (bf16_t*)alloc((size_t)BB * SS * FFD * 2);
  bf16_t* Wkb  = (bf16_t*)alloc((size_t)LL * DD * DD * 2);
  bf16_t* Wvb  = (bf16_t*)alloc((size_t)LL * DD * DD * 2);
  bf16_t* Wob  = (bf16_t*)alloc((size_t)LL * DD * DD * 2);
  bf16_t* W1b  = (bf16_t*)alloc((size_t)LL * DD * FFD * 2);
  bf16_t* W2b  = (bf16_t*)alloc((size_t)LL * FFD * DD * 2);

  pe_kernel<<<(SS * DD / 2 + 255) / 256, 256, 0, stream>>>(pe);
  tcast_kernel<<<dim3(DD / 32, DD / 32, LL), 256, 0, stream>>>(Wk, Wkb, DD, DD);
  tcast_kernel<<<dim3(DD / 32, DD / 32, LL), 256, 0, stream>>>(Wv, Wvb, DD, DD);
  tcast_kernel<<<dim3(DD / 32, DD / 32, LL), 256, 0, stream>>>(Wo, Wob, DD, DD);
  tcast_kernel<<<dim3(FFD / 32, DD / 32, LL), 256, 0, stream>>>(W1, W1b, DD, FFD);
  tcast_kernel<<<dim3(DD / 32, FFD / 32, LL), 256, 0, stream>>>(W2, W2b, FFD, DD);
  addpe_kernel<<<(int)(BSD / 4 / 256), 256, 0, stream>>>(q_emb, qa_emb, pe, x, xb, yb);

  const int M = BB * SS;
  const int nD8 = (M / 256) * (DD / 128);    // 256 blocks (1/CU)
  const int nF8 = (M / 256) * (FFD / 256);   // 512 blocks
  dim3 gA(SS / 128, HH, BB);       // paired q-tiles
  dim3 gV(SS / 64, HH, BB);        // vtrans
  for (int layer = 0; layer < LL; layer++) {
    const bf16_t* Wkl = Wkb + (size_t)layer * DD * DD;
    const bf16_t* Wvl = Wvb + (size_t)layer * DD * DD;
    const bf16_t* Wol = Wob + (size_t)layer * DD * DD;
    const bf16_t* W1l = W1b + (size_t)layer * DD * FFD;
    const bf16_t* W2l = W2b + (size_t)layer * FFD * DD;
    gemm8_kernel<128, true, false><<<nD8, 512, 0, stream>>>(xb, Wkl, bk + layer * DD, qkb, DD, DD, DD / 128);
    gemm8_kernel<128, true, false><<<nD8, 512, 0, stream>>>(yb, Wvl, bv + layer * DD, vbuf, DD, DD, DD / 128);
    vtrans_kernel<<<gV, 256, 0, stream>>>(vbuf, vtg);
    attn_kernel<<<gA, 256, 0, stream>>>(qkb, vtg, atb, bfp);
    gemm8_kernel<128, false, false><<<nD8, 512, 0, stream>>>(atb, Wol, bo + layer * DD, tmp, DD, DD, DD / 128);
    ln_kernel<<<M / 4, 256, 0, stream>>>(x, tmp, g1 + layer * DD, be1 + layer * DD, x, xb);
    gemm8_kernel<256, true, true><<<nF8, 512, 0, stream>>>(xb, W1l, b1 + layer * FFD, h1, FFD, DD, FFD / 256);
    gemm8_kernel<128, false, false><<<nD8, 512, 0, stream>>>(h1, W2l, b2 + layer * DD, tmp, DD, FFD, DD / 128);
    float* xo = (layer == LL - 1) ? out : x;
    ln_kernel<<<M / 4, 256, 0, stream>>>(x, tmp, g2 + layer * DD, be2 + layer * DD, xo, xb);
  }
}

// Round 7
// 828.526 us; speedup vs baseline: 1.3094x; 1.3094x over previous
//
#include <hip/hip_runtime.h>
#include <hip/hip_bf16.h>

typedef __bf16 bf16_t;
typedef __bf16 bf16x4 __attribute__((ext_vector_type(4)));
typedef __bf16 bf16x8 __attribute__((ext_vector_type(8)));
typedef float f32x4 __attribute__((ext_vector_type(4)));

union FragU { bf16x8 v; bf16x4 h[2]; };
union F4U { float4 v; float f[4]; };

constexpr int BB = 32, SS = 512, DD = 512, FFD = 2048, LL = 4, HH = 8;

// Fragment-order permutation of k within each 32-elem chunk: granule order
// [0,4,1,5,2,6,3,7] -> MFMA fragment g (k = 4g..4g+3, 16+4g..16+4g+3) is one
// contiguous 16B block at byte offset g*16 of the 64B chunk.
__device__ __forceinline__ int permk(int k) {
  int g = (k >> 2) & 7;
  int pos = (g < 4) ? (g << 1) : (((g - 4) << 1) | 1);
  return (k & ~31) | (pos << 2) | (k & 3);
}

__device__ __forceinline__ void gload_lds16(const bf16_t* g, bf16_t* l) {
  __builtin_amdgcn_global_load_lds(
      (const __attribute__((address_space(1))) void*)g,
      (__attribute__((address_space(3))) void*)l, 16, 0, 0);
}

template<int N> __device__ __forceinline__ void vmwait() {
  asm volatile("s_waitcnt vmcnt(%0)" :: "n"(N) : "memory");
}
__device__ __forceinline__ void barrier_raw() {
  asm volatile("s_barrier" ::: "memory");
}

// ---------------- positional-embedding table [S][D] ----------------
__global__ void pe_kernel(float* __restrict__ pe) {
  int idx = blockIdx.x * blockDim.x + threadIdx.x;  // pair index
  if (idx >= SS * DD / 2) return;
  int p = idx % (DD / 2);
  int s = idx / (DD / 2);
  float div = expf((float)(2 * p) * (-9.210340371976184f / (float)DD));
  float a = (float)s * div;
  pe[s * DD + 2 * p]     = sinf(a);
  pe[s * DD + 2 * p + 1] = cosf(a);
}

// ---------------- transpose-cast: src [K][N] f32 -> dst [N][K]_perm bf16 ----
__global__ __launch_bounds__(256) void tcast_kernel(const float* __restrict__ src,
                                                    bf16_t* __restrict__ dst,
                                                    int K, int N) {
  __shared__ float tile[32][33];
  size_t mat = (size_t)blockIdx.z * (size_t)K * (size_t)N;
  int k0 = blockIdx.y * 32, n0 = blockIdx.x * 32;
  int t = threadIdx.x;
  int r = t >> 3, c4 = (t & 7) * 4;
  const float4 v = *reinterpret_cast<const float4*>(&src[mat + (size_t)(k0 + r) * N + n0 + c4]);
  tile[r][c4 + 0] = v.x; tile[r][c4 + 1] = v.y; tile[r][c4 + 2] = v.z; tile[r][c4 + 3] = v.w;
  __syncthreads();
  bf16x4 o;
  o[0] = (bf16_t)tile[c4 + 0][r];
  o[1] = (bf16_t)tile[c4 + 1][r];
  o[2] = (bf16_t)tile[c4 + 2][r];
  o[3] = (bf16_t)tile[c4 + 3][r];
  *reinterpret_cast<bf16x4*>(&dst[mat + permk((n0 + r) * K + k0 + c4)]) = o;
}

// ---------------- x = q + pe (f32 + bf16_perm), yb = bf16_perm(qa + pe) ----
__global__ void addpe_kernel(const float* __restrict__ q, const float* __restrict__ qa,
                             const float* __restrict__ pe,
                             float* __restrict__ x, bf16_t* __restrict__ xb,
                             bf16_t* __restrict__ yb) {
  int i = blockIdx.x * blockDim.x + threadIdx.x;  // float4 index
  int pei = i & (SS * DD / 4 - 1);
  float4 pv = reinterpret_cast<const float4*>(pe)[pei];
  float4 qv = reinterpret_cast<const float4*>(q)[i];
  float4 av = reinterpret_cast<const float4*>(qa)[i];
  float4 xv = make_float4(qv.x + pv.x, qv.y + pv.y, qv.z + pv.z, qv.w + pv.w);
  float4 yv = make_float4(av.x + pv.x, av.y + pv.y, av.z + pv.z, av.w + pv.w);
  reinterpret_cast<float4*>(x)[i] = xv;
  bf16x4 xo, yo;
  xo[0] = (bf16_t)xv.x; xo[1] = (bf16_t)xv.y; xo[2] = (bf16_t)xv.z; xo[3] = (bf16_t)xv.w;
  yo[0] = (bf16_t)yv.x; yo[1] = (bf16_t)yv.y; yo[2] = (bf16_t)yv.z; yo[3] = (bf16_t)yv.w;
  int kp = permk(4 * i);
  *reinterpret_cast<bf16x4*>(&xb[kp]) = xo;
  *reinterpret_cast<bf16x4*>(&yb[kp]) = yo;
}

// ---------------- GEMM: C[M,N] = A[M,K]_perm @ Bt[N,K]_perm^T + bias ----------------
// 2-phase double-buffered BK=64 with COUNTED vmcnt (T4 graft): per tile
//   vmwait(8 = next tile's loads stay in flight) -> raw s_barrier -> ds_read+MFMA
//   -> raw s_barrier -> issue stage(T+2) into the buffer just consumed.
// Raw asm barriers avoid the compiler's vmcnt(0) drain; sched_barrier fences motion.
// OMODE: 0 = f32 row-major, 1 = bf16 permk row-major, 2 = V^T attn layout (vtg).
template<int OMODE, bool RELU>
__global__ __launch_bounds__(256, 2) void gemm_kernel(const bf16_t* __restrict__ A,
                                                      const bf16_t* __restrict__ Bt,
                                                      const float* __restrict__ bias,
                                                      void* __restrict__ Cout,
                                                      int N, int K, int nnt) {
  __shared__ bf16_t a_s[2][128 * 64];
  __shared__ bf16_t b_s[2][128 * 64];
  const int t = threadIdx.x;
  const int nwg = gridDim.x;
  const int bid = blockIdx.x;
  const int wg = (bid & 7) * (nwg >> 3) + (bid >> 3);   // bijective XCD swizzle
  const int m0 = (wg / nnt) * 128, n0 = (wg % nnt) * 128;
  const int l = t & 63, w = t >> 6, g = l >> 4, ln = l & 15;
  const int wm = (w >> 1) * 64, wn = (w & 1) * 64;
  // staging: round i covers LDS chunk c=i*256+t -> row i*32+(t>>3), blk t&7;
  // source block pre-swizzled: (t&7)^(row&7)
  const int tr = t >> 3;
  const int bsrc = ((t & 7) ^ (tr & 7)) * 8;
  const bf16_t* Asrc = A + (size_t)(m0 + tr) * K + bsrc;
  const bf16_t* Bsrc = Bt + (size_t)(n0 + tr) * K + bsrc;
  const size_t rstr = (size_t)32 * K;
  // read-side swizzled block offsets (row&7 == ln&7 for all fragment rows)
  const int x0 = (g ^ (ln & 7)) * 8;
  const int x1 = ((4 + g) ^ (ln & 7)) * 8;

  auto STAGE = [&](int p, int T) {
    const int k0 = T << 6;
#pragma unroll
    for (int i = 0; i < 4; i++) gload_lds16(Asrc + k0 + i * rstr, &a_s[p][(i * 256 + t) * 8]);
#pragma unroll
    for (int i = 0; i < 4; i++) gload_lds16(Bsrc + k0 + i * rstr, &b_s[p][(i * 256 + t) * 8]);
  };

  f32x4 acc[4][4] = {};
  const int NT = K >> 6;
  STAGE(0, 0);
  STAGE(1, 1);
  for (int T = 0; T < NT; T++) {
    const int p = T & 1;
    if (T + 1 < NT) vmwait<8>(); else vmwait<0>();   // own tile-T loads landed
    barrier_raw();                                   // all waves' tile-T loads landed
    __builtin_amdgcn_sched_barrier(0);
#pragma unroll
    for (int kc = 0; kc < 2; kc++) {
      const int xo = kc ? x1 : x0;
      FragU fa[4], fb[4];
#pragma unroll
      for (int mi = 0; mi < 4; mi++)
        fa[mi].v = *reinterpret_cast<const bf16x8*>(&a_s[p][(wm + mi * 16 + ln) * 64 + xo]);
#pragma unroll
      for (int ni = 0; ni < 4; ni++)
        fb[ni].v = *reinterpret_cast<const bf16x8*>(&b_s[p][(wn + ni * 16 + ln) * 64 + xo]);
      __builtin_amdgcn_s_setprio(1);
#pragma unroll
      for (int mi = 0; mi < 4; mi++)
#pragma unroll
        for (int ni = 0; ni < 4; ni++)
          acc[mi][ni] = __builtin_amdgcn_mfma_f32_16x16x32_bf16(fa[mi].v, fb[ni].v, acc[mi][ni], 0, 0, 0);
      __builtin_amdgcn_s_setprio(0);
    }
    __builtin_amdgcn_sched_barrier(0);
    barrier_raw();                                   // all waves done reading buffer p
    if (T + 2 < NT) STAGE(p, T + 2);                 // refill p; stays in flight
  }

  if constexpr (OMODE == 2) {
    // V^T write in attn's vtg layout: row=(b*H+h)*64+dd, 16B block blkx=(js*4+g)^(dd&7)
    const int brow = m0 >> 9;                 // batch (128-row tile never crosses 512)
    const int s0b = (m0 & 511) + wm;
    bf16_t* vout = reinterpret_cast<bf16_t*>(Cout);
#pragma unroll
    for (int ni = 0; ni < 4; ni++) {
      const int d = n0 + wn + ni * 16 + ln;
      const float bv = bias[d];
      const int h = d >> 6, dd = d & 63;
      bf16_t* vrow = vout + ((size_t)((brow * HH + h) * 64 + dd)) * SS;
#pragma unroll
      for (int mi = 0; mi < 4; mi++) {
        const int s0 = s0b + mi * 16 + g * 4;
        const int jt = s0 >> 6, jj = s0 & 63;
        const int js = jj >> 5, half = (jj >> 4) & 1;
        const int blkx = (js * 4 + g) ^ (dd & 7);
        bf16x4 o;
#pragma unroll
        for (int r = 0; r < 4; r++) o[r] = (bf16_t)(acc[mi][ni][r] + bv);
        *reinterpret_cast<bf16x4*>(&vrow[jt * 64 + blkx * 8 + half * 4]) = o;
      }
    }
  } else {
#pragma unroll
    for (int ni = 0; ni < 4; ni++) {
      const int col = n0 + wn + ni * 16 + ln;
      const float bv = bias[col];
      const int colp = (OMODE == 1) ? permk(col) : col;
#pragma unroll
      for (int mi = 0; mi < 4; mi++)
#pragma unroll
        for (int r = 0; r < 4; r++) {
          int row = m0 + wm + mi * 16 + g * 4 + r;
          float o = acc[mi][ni][r] + bv;
          if (RELU) o = fmaxf(o, 0.f);
          if (OMODE == 1)
            reinterpret_cast<bf16_t*>(Cout)[(size_t)row * N + colp] = (bf16_t)o;
          else
            reinterpret_cast<float*>(Cout)[(size_t)row * N + col] = o;
        }
    }
  }
}

// ---------------- residual + LayerNorm: xout=LN(xin+addv), bf16_perm copy ----
__global__ __launch_bounds__(256) void ln_kernel(const float* __restrict__ xin,
                                                 const float* __restrict__ addv,
                                                 const float* __restrict__ gamma,
                                                 const float* __restrict__ beta,
                                                 float* __restrict__ xout,
                                                 bf16_t* __restrict__ xbout) {
  int row = blockIdx.x * 4 + (threadIdx.x >> 6);
  int l = threadIdx.x & 63;
  const float* px = xin + (size_t)row * DD;
  const float* pa = addv + (size_t)row * DD;
  float vals[8];
  float s = 0.f;
#pragma unroll
  for (int i = 0; i < 2; i++) {
    float4 a = reinterpret_cast<const float4*>(px)[l * 2 + i];
    float4 b = reinterpret_cast<const float4*>(pa)[l * 2 + i];
    vals[i * 4 + 0] = a.x + b.x;
    vals[i * 4 + 1] = a.y + b.y;
    vals[i * 4 + 2] = a.z + b.z;
    vals[i * 4 + 3] = a.w + b.w;
  }
#pragma unroll
  for (int j = 0; j < 8; j++) s += vals[j];
#pragma unroll
  for (int off = 1; off < 64; off <<= 1) s += __shfl_xor(s, off, 64);
  float mean = s * (1.f / DD);
  float sq = 0.f;
#pragma unroll
  for (int j = 0; j < 8; j++) { float d = vals[j] - mean; sq += d * d; }
#pragma unroll
  for (int off = 1; off < 64; off <<= 1) sq += __shfl_xor(sq, off, 64);
  float rstd = rsqrtf(sq * (1.f / DD) + 1e-5f);
#pragma unroll
  for (int i = 0; i < 2; i++) {
    F4U o; bf16x4 ob;
#pragma unroll
    for (int j = 0; j < 4; j++) {
      int colj = l * 8 + i * 4 + j;
      float v = (vals[i * 4 + j] - mean) * rstd * gamma[colj] + beta[colj];
      o.f[j] = v;
      ob[j] = (bf16_t)v;
    }
    reinterpret_cast<float4*>(xout + (size_t)row * DD)[l * 2 + i] = o.v;
    *reinterpret_cast<bf16x4*>(&xbout[(size_t)row * DD + permk(l * 8 + i * 4)]) = ob;
  }
}

// ---------------- fused causal attention, swapped-QK^T (S^T), V^T pre-staged ----------
__global__ __launch_bounds__(256) void attn_kernel(const bf16_t* __restrict__ qk,
                                                   const bf16_t* __restrict__ vtg,
                                                   bf16_t* __restrict__ outp,
                                                   const float* __restrict__ bfp) {
  __shared__ bf16_t k_s[64 * 64];    // K tile, block-XOR pre-swizzled via source
  __shared__ bf16_t v_t[64 * 64];    // V^T tile, swizzle baked in global layout
  const int bx = blockIdx.x, h = blockIdx.y, b = blockIdx.z;
  const int t = threadIdx.x, l = t & 63, w = t >> 6, g = l >> 4, ln = l & 15;
  const float sc = 0.125f * (1.f + bfp[0]);
  const size_t base = ((size_t)b * SS) * DD + h * 64;
  const bf16_t* vbase = vtg + ((size_t)((b * HH + h) * 64)) * SS;
  const int NQT = SS / 64;

  for (int pass = 0; pass < 2; pass++) {
    const int qt = pass ? (NQT - 1 - bx) : bx;
    const int i0 = qt * 64;
    FragU qB[2];   // wave's 16 q-rows as B-operand: lane(g,ln) = Q[i0+w*16+ln][frag g]
    {
      const bf16_t* qp = qk + base + (size_t)(i0 + w * 16 + ln) * DD;
      qB[0].v = *reinterpret_cast<const bf16x8*>(&qp[g * 8]);
      qB[1].v = *reinterpret_cast<const bf16x8*>(&qp[32 + g * 8]);
    }
    float m = -1e30f, lrow = 0.f;   // softmax state for row i = i0 + w*16 + ln
    f32x4 acc[4] = {};              // O rows i0+w*16+g*4+r, cols d = nd*16+ln
    const int iql = w * 16 + ln;

    for (int kt = 0; kt <= qt; kt++) {
      const int j0 = kt * 64;
      __syncthreads();
      {
        int c1 = t + 256;
        int jr0 = t >> 3, bb0 = t & 7;
        int jr1 = c1 >> 3, bb1 = c1 & 7;
        gload_lds16(qk + base + (size_t)(j0 + jr0) * DD + ((bb0 ^ (jr0 & 7)) * 8), &k_s[t * 8]);
        gload_lds16(qk + base + (size_t)(j0 + jr1) * DD + ((bb1 ^ (jr1 & 7)) * 8), &k_s[c1 * 8]);
        gload_lds16(vbase + (size_t)jr0 * SS + j0 + bb0 * 8, &v_t[t * 8]);
        gload_lds16(vbase + (size_t)jr1 * SS + j0 + bb1 * 8, &v_t[c1 * 8]);
      }
      asm volatile("s_waitcnt vmcnt(0)" ::: "memory");
      __syncthreads();
      // S^T: sfr[nj] holds rows j = j0+nj*16+g*4+r, col i = i0+w*16+ln
      f32x4 sfr[4] = {};
#pragma unroll
      for (int ks = 0; ks < 2; ks++)
#pragma unroll
        for (int nj = 0; nj < 4; nj++) {
          int jc = nj * 16 + ln;
          FragU ka;
          ka.v = *reinterpret_cast<const bf16x8*>(&k_s[jc * 64 + (((ks * 4 + g) ^ (jc & 7)) * 8)]);
          sfr[nj] = __builtin_amdgcn_mfma_f32_16x16x32_bf16(ka.v, qB[ks].v, sfr[nj], 0, 0, 0);
        }
      if (kt == qt) {   // strictly-causal mask, diag tile only
#pragma unroll
        for (int nj = 0; nj < 4; nj++)
#pragma unroll
          for (int r = 0; r < 4; r++)
            if (nj * 16 + g * 4 + r >= iql) sfr[nj][r] = -1e30f;
      }
      float pm = -1e30f;
#pragma unroll
      for (int nj = 0; nj < 4; nj++)
#pragma unroll
        for (int r = 0; r < 4; r++) pm = fmaxf(pm, sfr[nj][r]);
      pm = fmaxf(pm, __shfl_xor(pm, 16, 64));
      pm = fmaxf(pm, __shfl_xor(pm, 32, 64));
      float mnew = fmaxf(m, pm);
      float fac = __expf(sc * (m - mnew));
      m = mnew;
      float ps = 0.f;
#pragma unroll
      for (int nj = 0; nj < 4; nj++)
#pragma unroll
        for (int r = 0; r < 4; r++) {
          float p = __expf(sc * (sfr[nj][r] - m));   // masked -> exp(-inf) = 0
          sfr[nj][r] = p;
          ps += p;
        }
      ps += __shfl_xor(ps, 16, 64);
      ps += __shfl_xor(ps, 32, 64);
      lrow = lrow * fac + ps;
      float facr[4];
#pragma unroll
      for (int r = 0; r < 4; r++) facr[r] = __shfl(fac, g * 4 + r, 64);
#pragma unroll
      for (int nd = 0; nd < 4; nd++)
#pragma unroll
        for (int r = 0; r < 4; r++) acc[nd][r] *= facr[r];
      // P fragments: A-operand layout == swapped-MFMA C layout (same lane)
      FragU pa[2];
#pragma unroll
      for (int js = 0; js < 2; js++)
#pragma unroll
        for (int kk = 0; kk < 4; kk++) {
          pa[js].v[kk]     = (bf16_t)sfr[js * 2][kk];
          pa[js].v[kk + 4] = (bf16_t)sfr[js * 2 + 1][kk];
        }
#pragma unroll
      for (int js = 0; js < 2; js++)
#pragma unroll
        for (int nd = 0; nd < 4; nd++) {
          int d = nd * 16 + ln;
          FragU vb;
          vb.v = *reinterpret_cast<const bf16x8*>(&v_t[d * 64 + (((js * 4 + g) ^ (d & 7)) * 8)]);
          acc[nd] = __builtin_amdgcn_mfma_f32_16x16x32_bf16(pa[js].v, vb.v, acc[nd], 0, 0, 0);
        }
    }
    float lr[4];
#pragma unroll
    for (int r = 0; r < 4; r++) lr[r] = __shfl(lrow, g * 4 + r, 64);
    const int orow0 = i0 + w * 16 + g * 4;
#pragma unroll
    for (int nd = 0; nd < 4; nd++) {
      const int colp = permk(nd * 16 + ln);
#pragma unroll
      for (int r = 0; r < 4; r++) {
        int grow = orow0 + r;
        float o = (grow > 0 && lr[r] > 0.f) ? acc[nd][r] / lr[r] : 0.f;  // row0 zero_pad
        outp[base + (size_t)grow * DD + colp] = (bf16_t)o;
      }
    }
  }
}

extern "C" void kernel_launch(void* const* d_in, const int* in_sizes, int n_in,
                              void* d_out, int out_size, void* d_ws, size_t ws_size,
                              hipStream_t stream) {
  const float* q_emb  = (const float*)d_in[0];
  const float* qa_emb = (const float*)d_in[1];
  const float* bfp    = (const float*)d_in[2];
  const float* Wk  = (const float*)d_in[3];
  const float* bk  = (const float*)d_in[4];
  const float* Wv  = (const float*)d_in[5];
  const float* bv  = (const float*)d_in[6];
  const float* Wo  = (const float*)d_in[7];
  const float* bo  = (const float*)d_in[8];
  const float* g1  = (const float*)d_in[9];
  const float* be1 = (const float*)d_in[10];
  const float* W1  = (const float*)d_in[11];
  const float* b1  = (const float*)d_in[12];
  const float* W2  = (const float*)d_in[13];
  const float* b2  = (const float*)d_in[14];
  const float* g2  = (const float*)d_in[15];
  const float* be2 = (const float*)d_in[16];
  float* out = (float*)d_out;
  (void)in_sizes; (void)n_in; (void)out_size; (void)ws_size;

  char* wsp = (char*)d_ws;
  size_t off = 0;
  auto alloc = [&](size_t bytes) -> void* {
    void* p = wsp + off;
    off += (bytes + 255) & ~(size_t)255;
    return p;
  };
  const size_t BSD = (size_t)BB * SS * DD;
  float*  pe   = (float*) alloc((size_t)SS * DD * 4);
  float*  x    = (float*) alloc(BSD * 4);
  float*  tmp  = (float*) alloc(BSD * 4);
  bf16_t* xb   = (bf16_t*)alloc(BSD * 2);
  bf16_t* yb   = (bf16_t*)alloc(BSD * 2);
  bf16_t* qkb  = (bf16_t*)alloc(BSD * 2);
  bf16_t* vtg  = (bf16_t*)alloc(BSD * 2);
  bf16_t* atb  = (bf16_t*)alloc(BSD * 2);
  bf16_t* h1   = (bf16_t*)alloc((size_t)BB * SS * FFD * 2);
  bf16_t* Wkb  = (bf16_t*)alloc((size_t)LL * DD * DD * 2);
  bf16_t* Wvb  = (bf16_t*)alloc((size_t)LL * DD * DD * 2);
  bf16_t* Wob  = (bf16_t*)alloc((size_t)LL * DD * DD * 2);
  bf16_t* W1b  = (bf16_t*)alloc((size_t)LL * DD * FFD * 2);
  bf16_t* W2b  = (bf16_t*)alloc((size_t)LL * FFD * DD * 2);

  pe_kernel<<<(SS * DD / 2 + 255) / 256, 256, 0, stream>>>(pe);
  tcast_kernel<<<dim3(DD / 32, DD / 32, LL), 256, 0, stream>>>(Wk, Wkb, DD, DD);
  tcast_kernel<<<dim3(DD / 32, DD / 32, LL), 256, 0, stream>>>(Wv, Wvb, DD, DD);
  tcast_kernel<<<dim3(DD / 32, DD / 32, LL), 256, 0, stream>>>(Wo, Wob, DD, DD);
  tcast_kernel<<<dim3(FFD / 32, DD / 32, LL), 256, 0, stream>>>(W1, W1b, DD, FFD);
  tcast_kernel<<<dim3(DD / 32, FFD / 32, LL), 256, 0, stream>>>(W2, W2b, FFD, DD);
  addpe_kernel<<<(int)(BSD / 4 / 256), 256, 0, stream>>>(q_emb, qa_emb, pe, x, xb, yb);

  const int M = BB * SS;
  const int nD = (M / 128) * (DD / 128);    // 512 blocks
  const int nF = (M / 128) * (FFD / 128);   // 2048 blocks
  dim3 gA(SS / 128, HH, BB);       // paired q-tiles
  for (int layer = 0; layer < LL; layer++) {
    const bf16_t* Wkl = Wkb + (size_t)layer * DD * DD;
    const bf16_t* Wvl = Wvb + (size_t)layer * DD * DD;
    const bf16_t* Wol = Wob + (size_t)layer * DD * DD;
    const bf16_t* W1l = W1b + (size_t)layer * DD * FFD;
    const bf16_t* W2l = W2b + (size_t)layer * FFD * DD;
    gemm_kernel<1, false><<<nD, 256, 0, stream>>>(xb, Wkl, bk + layer * DD, qkb, DD, DD, DD / 128);
    gemm_kernel<2, false><<<nD, 256, 0, stream>>>(yb, Wvl, bv + layer * DD, vtg, DD, DD, DD / 128);
    attn_kernel<<<gA, 256, 0, stream>>>(qkb, vtg, atb, bfp);
    gemm_kernel<0, false><<<nD, 256, 0, stream>>>(atb, Wol, bo + layer * DD, tmp, DD, DD, DD / 128);
    ln_kernel<<<M / 4, 256, 0, stream>>>(x, tmp, g1 + layer * DD, be1 + layer * DD, x, xb);
    gemm_kernel<1, true><<<nF, 256, 0, stream>>>(xb, W1l, b1 + layer * FFD, h1, FFD, DD, FFD / 128);
    gemm_kernel<0, false><<<nD, 256, 0, stream>>>(h1, W2l, b2 + layer * DD, tmp, DD, FFD, DD / 128);
    float* xo = (layer == LL - 1) ? out : x;
    ln_kernel<<<M / 4, 256, 0, stream>>>(x, tmp, g2 + layer * DD, be2 + layer * DD, xo, xb);
  }
}